// Round 19
// baseline (91.390 us; speedup 1.0000x reference)
//
#include <hip/hip_runtime.h>

#define NB 16          // batch
#define NH 512
#define NW 512

// db2 decomposition filters
__device__ __constant__ float DLO[4] = {-0.12940952255092145f, 0.22414386804185735f, 0.836516303737469f, 0.48296291314469025f};
__device__ __constant__ float DHI[4] = {-0.48296291314469025f, 0.836516303737469f, -0.22414386804185735f, -0.12940952255092145f};

__device__ inline float wave_max(float v) {
    #pragma unroll
    for (int off = 32; off; off >>= 1) v = fmaxf(v, __shfl_xor(v, off, 64));
    return v;
}

// Level-1 DWT, 4 output rows per block: grid (64, NB), 256 threads = 256 columns.
__global__ __launch_bounds__(256) void k_dwt1(const float* __restrict__ x,
                                              const float* __restrict__ hfw,
                                              float* __restrict__ arr_hf,
                                              float* __restrict__ a1,
                                              float* __restrict__ pbmax1) {
    int b  = blockIdx.y;
    int r0 = blockIdx.x << 2;            // first of 4 output rows
    int c  = threadIdx.x;                // 0..255
    const float* xb = x + (size_t)b * (NH * NW);
    float* arr = arr_hf + (size_t)b * (512 * 512);

    int ca  = (2 * c - 2 + 512) & 511;   // wrapped col pair (2c-2, 2c-1) -- always contiguous
    int cbp = 2 * c;                     // col pair (2c, 2c+1)

    float X[4][4];                        // X[k][l] = x[(2r-2+k)&511][(2c-2+l)&511]
    #pragma unroll
    for (int k = 0; k < 4; ++k) {
        int rr = (2 * r0 - 2 + k + 512) & 511;
        float2 u0 = *(const float2*)(xb + rr * 512 + ca);
        float2 u1 = *(const float2*)(xb + rr * 512 + cbp);
        X[k][0] = u0.x; X[k][1] = u0.y; X[k][2] = u1.x; X[k][3] = u1.y;
    }

    float mad = 0.f, mda = 0.f, mdd = 0.f;

    #pragma unroll
    for (int s = 0; s < 4; ++s) {
        int r = r0 + s;

        float lo[4], hi[4];
        #pragma unroll
        for (int l = 0; l < 4; ++l) {
            float alo = 0.f, ahi = 0.f;
            #pragma unroll
            for (int k = 0; k < 4; ++k) { alo += DLO[3 - k] * X[k][l]; ahi += DHI[3 - k] * X[k][l]; }
            lo[l] = alo; hi[l] = ahi;
        }
        float va = 0.f, vad = 0.f, vda = 0.f, vdd = 0.f;
        #pragma unroll
        for (int l = 0; l < 4; ++l) {
            va  += DLO[3 - l] * lo[l];
            vad += DHI[3 - l] * lo[l];
            vda += DLO[3 - l] * hi[l];
            vdd += DHI[3 - l] * hi[l];
        }

        a1[b * 65536 + r * 256 + c] = va;
        int p_tr = r * 512 + (c + 256);
        int p_bl = (r + 256) * 512 + c;
        int p_br = (r + 256) * 512 + (c + 256);
        arr[p_tr] = vad * hfw[p_tr];
        arr[p_bl] = vda * hfw[p_bl];
        arr[p_br] = vdd * hfw[p_br];

        mad = fmaxf(mad, fabsf(vad));
        mda = fmaxf(mda, fabsf(vda));
        mdd = fmaxf(mdd, fabsf(vdd));

        if (s < 3) {
            #pragma unroll
            for (int l = 0; l < 4; ++l) { X[0][l] = X[2][l]; X[1][l] = X[3][l]; }
            int rr2 = 2 * r + 2;          // <= 510, no wrap needed
            float2 u0 = *(const float2*)(xb + rr2 * 512 + ca);
            float2 u1 = *(const float2*)(xb + rr2 * 512 + cbp);
            X[2][0] = u0.x; X[2][1] = u0.y; X[2][2] = u1.x; X[2][3] = u1.y;
            float2 w0 = *(const float2*)(xb + (rr2 + 1) * 512 + ca);
            float2 w1 = *(const float2*)(xb + (rr2 + 1) * 512 + cbp);
            X[3][0] = w0.x; X[3][1] = w0.y; X[3][2] = w1.x; X[3][3] = w1.y;
        }
    }

    __shared__ float wmax[4][3];
    int wv = threadIdx.x >> 6, ln = threadIdx.x & 63;
    float m0 = wave_max(mad);
    float m1 = wave_max(mda);
    float m2 = wave_max(mdd);
    if (ln == 0) { wmax[wv][0] = m0; wmax[wv][1] = m1; wmax[wv][2] = m2; }
    __syncthreads();
    if (threadIdx.x < 3) {
        int i = threadIdx.x;
        float m = fmaxf(fmaxf(wmax[0][i], wmax[1][i]), fmaxf(wmax[2][i], wmax[3][i]));
        pbmax1[(b * 64 + blockIdx.x) * 3 + i] = m;
    }
}

// Level-2 DWT: a1 -> (a2,ad2,da2,dd2)*hfw into arr top-left; g2 = a2*lfw.
__global__ __launch_bounds__(256) void k_dwt2(const float* __restrict__ a1,
                                              const float* __restrict__ hfw,
                                              const float* __restrict__ lfw,
                                              float* __restrict__ arr_hf,
                                              float* __restrict__ g2,
                                              const float* __restrict__ pbmax1,
                                              float* __restrict__ pbmax2,
                                              float* __restrict__ maxbuf) {
    int b = blockIdx.y;
    int idx = blockIdx.x * 256 + threadIdx.x;
    int r = idx >> 7, c = idx & 127;
    const float* ab = a1 + b * 65536;

    float X[4][4];
    if (r >= 1 && c >= 1) {
        const float* p = ab + (2 * r - 2) * 256 + (2 * c - 2);
        #pragma unroll
        for (int k = 0; k < 4; ++k) {
            float2 u0 = *(const float2*)(p + k * 256);
            float2 u1 = *(const float2*)(p + k * 256 + 2);
            X[k][0] = u0.x; X[k][1] = u0.y; X[k][2] = u1.x; X[k][3] = u1.y;
        }
    } else {
        #pragma unroll
        for (int k = 0; k < 4; ++k) {
            int rr = (2 * r - 2 + k + 256) & 255;
            #pragma unroll
            for (int l = 0; l < 4; ++l) {
                int cc = (2 * c - 2 + l + 256) & 255;
                X[k][l] = ab[rr * 256 + cc];
            }
        }
    }
    float lo[4], hi[4];
    #pragma unroll
    for (int l = 0; l < 4; ++l) {
        float alo = 0.f, ahi = 0.f;
        #pragma unroll
        for (int k = 0; k < 4; ++k) { alo += DLO[3 - k] * X[k][l]; ahi += DHI[3 - k] * X[k][l]; }
        lo[l] = alo; hi[l] = ahi;
    }
    float va = 0.f, vad = 0.f, vda = 0.f, vdd = 0.f;
    #pragma unroll
    for (int l = 0; l < 4; ++l) {
        va  += DLO[3 - l] * lo[l];
        vad += DHI[3 - l] * lo[l];
        vda += DLO[3 - l] * hi[l];
        vdd += DHI[3 - l] * hi[l];
    }

    g2[b * 16384 + r * 128 + c] = va * lfw[r * 128 + c];
    float* arr = arr_hf + (size_t)b * (512 * 512);
    int p_tl = r * 512 + c;
    int p_tr = r * 512 + (c + 128);
    int p_bl = (r + 128) * 512 + c;
    int p_br = (r + 128) * 512 + (c + 128);
    arr[p_tl] = va  * hfw[p_tl];
    arr[p_tr] = vad * hfw[p_tr];
    arr[p_bl] = vda * hfw[p_bl];
    arr[p_br] = vdd * hfw[p_br];

    __shared__ float wmax[4][4];
    int wv = threadIdx.x >> 6, ln = threadIdx.x & 63;
    float m0 = wave_max(fabsf(va));
    float m1 = wave_max(fabsf(vad));
    float m2 = wave_max(fabsf(vda));
    float m3 = wave_max(fabsf(vdd));
    if (ln == 0) { wmax[wv][0] = m0; wmax[wv][1] = m1; wmax[wv][2] = m2; wmax[wv][3] = m3; }
    __syncthreads();
    if (threadIdx.x < 4) {
        int i = threadIdx.x;
        float m = fmaxf(fmaxf(wmax[0][i], wmax[1][i]), fmaxf(wmax[2][i], wmax[3][i]));
        pbmax2[(b * 64 + blockIdx.x) * 4 + i] = m;
    }

    // block 0 of each batch: reduce dwt1's 64x3 per-block maxes -> level-1 finals
    if (blockIdx.x == 0 && threadIdx.x < 64) {
        const float* p1 = pbmax1 + (size_t)(b * 64 + threadIdx.x) * 3;
        float q0 = wave_max(p1[0]);
        float q1 = wave_max(p1[1]);
        float q2 = wave_max(p1[2]);
        if (threadIdx.x == 0) {
            maxbuf[b * 8 + 0] = q0;
            maxbuf[b * 8 + 1] = q1;
            maxbuf[b * 8 + 2] = q2;
        }
    }
}

// select normalization reciprocal by quadrant
__device__ __forceinline__ float quad_inv(int gh, int gw,
                                          float inv_ad1, float inv_da1, float inv_dd1,
                                          float inv_a2, float inv_ad2, float inv_da2, float inv_dd2) {
    if (gh < 256) {
        if (gw < 256) {
            if (gh < 128) return (gw < 128) ? inv_a2 : inv_ad2;
            else          return (gw < 128) ? inv_da2 : inv_dd2;
        }
        return inv_ad1;
    }
    return (gw < 256) ? inv_da1 : inv_dd1;
}

// bilinear sample of g2 (a2*lfw) at output pixel (gh,gw); * inv_a2 applied by caller
__device__ __forceinline__ float bilin_g2(const float* __restrict__ g2b, int gh, int gw) {
    float sh = fminf(fmaxf(0.25f * (float)gh - 0.375f, 0.f), 127.f);
    float sw = fminf(fmaxf(0.25f * (float)gw - 0.375f, 0.f), 127.f);
    int r0 = (int)sh; float fr = sh - (float)r0; int r1 = min(r0 + 1, 127);
    int c0 = (int)sw; float fc = sw - (float)c0; int c1 = min(c0 + 1, 127);
    float g00 = g2b[r0 * 128 + c0];
    float g01 = g2b[r0 * 128 + c1];
    float g10 = g2b[r1 * 128 + c0];
    float g11 = g2b[r1 * 128 + c1];
    float t0 = g00 * (1.f - fr) + g10 * fr;
    float t1 = g01 * (1.f - fr) + g11 * fr;
    return t0 * (1.f - fc) + t1 * fc;
}

// Fused conv stage: 256-wide x 8-row tiles, 512 threads, 2-tile pipeline, 8-oc passes.
// ONLY intended delta vs R16/R18: a wave (row=tid>>6, q=tid&63) now stores a FULL
// 256-col row = 1 KB contiguous per wave-store (vs 512 B with 128-wide tiles).
// Halo (10/8), per-thread work (4 px/tile, acc[8][4]=32 VGPR), occupancy unchanged.
__global__ __launch_bounds__(512) void k_conv(const float* __restrict__ arr_hf,
                                              const float* __restrict__ g2,
                                              const float* __restrict__ maxbuf,
                                              const float* __restrict__ pbmax2,
                                              const float* __restrict__ cw,
                                              const float* __restrict__ cb,
                                              float* __restrict__ out) {
    int b   = blockIdx.z;
    int th0 = blockIdx.y * 16;           // tile0: rows th0..th0+7, tile1: +8
    int tw0 = blockIdx.x * 256;
    int tid = threadIdx.x;

    __shared__ __align__(16) float tile[2][2][10][260];   // [buf][ch][row][col]
    __shared__ float l2max[4];

    // wave 0: reduce level-2 per-block maxes (64 float4, L2-hot)
    if (tid < 64) {
        float4 m4 = *(const float4*)(pbmax2 + (size_t)(b * 64 + tid) * 4);
        float q0 = wave_max(m4.x);
        float q1 = wave_max(m4.y);
        float q2 = wave_max(m4.z);
        float q3 = wave_max(m4.w);
        if (tid == 0) { l2max[0] = q0; l2max[1] = q1; l2max[2] = q2; l2max[3] = q3; }
    }
    __syncthreads();

    float inv_ad1 = 1.f / maxbuf[b * 8 + 0];
    float inv_da1 = 1.f / maxbuf[b * 8 + 1];
    float inv_dd1 = 1.f / maxbuf[b * 8 + 2];
    float inv_a2  = 1.f / l2max[0];
    float inv_ad2 = 1.f / l2max[1];
    float inv_da2 = 1.f / l2max[2];
    float inv_dd2 = 1.f / l2max[3];

    const float* arr = arr_hf + (size_t)b * (512 * 512);
    const float* g2b = g2 + b * 16384;

    int q   = tid & 63;   // quad: cols 4q..4q+3 of the 256-wide tile
    int row = tid >> 6;   // output row within tile: 0..7
    size_t plane = 512 * 512;

    // ---- stage tile0 (10 rows x 258 cols) ----
    for (int i = tid; i < 10 * 258; i += 512) {
        int r_ = i / 258;
        int col = i - r_ * 258;
        int gh = th0 + r_ - 1;
        int gw = tw0 + col - 1;
        float v0 = 0.f, v1 = 0.f;
        if (gh >= 0 && gh < 512 && gw >= 0 && gw < 512) {
            v0 = arr[gh * 512 + gw] * quad_inv(gh, gw, inv_ad1, inv_da1, inv_dd1, inv_a2, inv_ad2, inv_da2, inv_dd2);
            v1 = bilin_g2(g2b, gh, gw) * inv_a2;
        }
        tile[0][0][r_][col] = v0;
        tile[0][1][r_][col] = v1;
    }
    __syncthreads();

    // ---- prefetch tile1's arr values into registers ----
    float pre[6];
    #pragma unroll
    for (int it = 0; it < 6; ++it) {
        int i = tid + it * 512;
        float pv = 0.f;
        if (i < 2580) {
            int r_ = i / 258;
            int col = i - r_ * 258;
            int gh = th0 + 8 + r_ - 1;
            int gw = tw0 + col - 1;
            if (gh < 512 && gw >= 0 && gw < 512) pv = arr[gh * 512 + gw];
        }
        pre[it] = pv;
    }

    // ---- compute + store tile0 (two 8-oc passes) ----
    #pragma unroll 1
    for (int half = 0; half < 2; ++half) {
        float acc[8][4];
        #pragma unroll
        for (int oc = 0; oc < 8; ++oc) {
            float bvv = cb[half * 8 + oc];
            #pragma unroll
            for (int j = 0; j < 4; ++j) acc[oc][j] = bvv;
        }
        #pragma unroll
        for (int ic = 0; ic < 2; ++ic)
            #pragma unroll
            for (int kh = 0; kh < 3; ++kh) {
                const float* rp_ = &tile[0][ic][row + kh][4 * q];
                float v[6];
                { float4 t = *(const float4*)rp_; v[0] = t.x; v[1] = t.y; v[2] = t.z; v[3] = t.w;
                  float2 s = *(const float2*)(rp_ + 4); v[4] = s.x; v[5] = s.y; }
                #pragma unroll
                for (int kw = 0; kw < 3; ++kw)
                    #pragma unroll
                    for (int oc = 0; oc < 8; ++oc) {
                        float wv = cw[(half * 8 + oc) * 18 + ic * 9 + kh * 3 + kw];
                        #pragma unroll
                        for (int j = 0; j < 4; ++j)
                            acc[oc][j] = fmaf(v[j + kw], wv, acc[oc][j]);
                    }
            }
        float* ob = out + (size_t)(b * 16 + half * 8) * plane + (size_t)(th0 + row) * 512 + tw0 + 4 * q;
        #pragma unroll
        for (int oc = 0; oc < 8; ++oc) {
            float4 val = make_float4(acc[oc][0], acc[oc][1], acc[oc][2], acc[oc][3]);
            *(float4*)(ob + (size_t)oc * plane) = val;
        }
    }

    // ---- finish staging tile1 ----
    #pragma unroll
    for (int it = 0; it < 6; ++it) {
        int i = tid + it * 512;
        if (i < 2580) {
            int r_ = i / 258;
            int col = i - r_ * 258;
            int gh = th0 + 8 + r_ - 1;
            int gw = tw0 + col - 1;
            float v0 = 0.f, v1 = 0.f;
            if (gh < 512 && gw >= 0 && gw < 512) {
                v0 = pre[it] * quad_inv(gh, gw, inv_ad1, inv_da1, inv_dd1, inv_a2, inv_ad2, inv_da2, inv_dd2);
                v1 = bilin_g2(g2b, gh, gw) * inv_a2;
            }
            tile[1][0][r_][col] = v0;
            tile[1][1][r_][col] = v1;
        }
    }
    __syncthreads();

    // ---- compute + store tile1 (two 8-oc passes) ----
    #pragma unroll 1
    for (int half = 0; half < 2; ++half) {
        float acc[8][4];
        #pragma unroll
        for (int oc = 0; oc < 8; ++oc) {
            float bvv = cb[half * 8 + oc];
            #pragma unroll
            for (int j = 0; j < 4; ++j) acc[oc][j] = bvv;
        }
        #pragma unroll
        for (int ic = 0; ic < 2; ++ic)
            #pragma unroll
            for (int kh = 0; kh < 3; ++kh) {
                const float* rp_ = &tile[1][ic][row + kh][4 * q];
                float v[6];
                { float4 t = *(const float4*)rp_; v[0] = t.x; v[1] = t.y; v[2] = t.z; v[3] = t.w;
                  float2 s = *(const float2*)(rp_ + 4); v[4] = s.x; v[5] = s.y; }
                #pragma unroll
                for (int kw = 0; kw < 3; ++kw)
                    #pragma unroll
                    for (int oc = 0; oc < 8; ++oc) {
                        float wv = cw[(half * 8 + oc) * 18 + ic * 9 + kh * 3 + kw];
                        #pragma unroll
                        for (int j = 0; j < 4; ++j)
                            acc[oc][j] = fmaf(v[j + kw], wv, acc[oc][j]);
                    }
            }
        float* ob = out + (size_t)(b * 16 + half * 8) * plane + (size_t)(th0 + 8 + row) * 512 + tw0 + 4 * q;
        #pragma unroll
        for (int oc = 0; oc < 8; ++oc) {
            float4 val = make_float4(acc[oc][0], acc[oc][1], acc[oc][2], acc[oc][3]);
            *(float4*)(ob + (size_t)oc * plane) = val;
        }
    }
}

extern "C" void kernel_launch(void* const* d_in, const int* in_sizes, int n_in,
                              void* d_out, int out_size, void* d_ws, size_t ws_size,
                              hipStream_t stream) {
    const float* x   = (const float*)d_in[0];
    const float* hfw = (const float*)d_in[1];
    const float* lfw = (const float*)d_in[2];
    const float* cw  = (const float*)d_in[3];
    const float* cb  = (const float*)d_in[4];
    float* out = (float*)d_out;

    char* ws = (char*)d_ws;
    float* arr_hf = (float*)(ws);                    // 16 MiB: 16 x 512 x 512 (pre-multiplied by hfw)
    float* a1     = (float*)(ws + 16777216);         //  4 MiB: 16 x 256 x 256
    float* g2     = (float*)(ws + 20971520);         //  1 MiB: 16 x 128 x 128 (a2 * lfw)
    float* maxbuf = (float*)(ws + 22020096);         //  16 x 8 f32 (level-1 finals)
    float* pbmax1 = (float*)(ws + 22020608);         //  16 x 64 x 3 f32
    float* pbmax2 = (float*)(ws + 22033408);         //  16 x 64 x 4 f32 (float4-aligned)

    k_dwt1<<<dim3(64, NB), 256, 0, stream>>>(x, hfw, arr_hf, a1, pbmax1);
    k_dwt2<<<dim3(64, NB), 256, 0, stream>>>(a1, hfw, lfw, arr_hf, g2, pbmax1, pbmax2, maxbuf);
    k_conv<<<dim3(2, 32, NB), 512, 0, stream>>>(arr_hf, g2, maxbuf, pbmax2, cw, cb, out);
}

// Round 20
// 79.792 us; speedup vs baseline: 1.1454x; 1.1454x over previous
//
#include <hip/hip_runtime.h>

#define NB 16          // batch
#define NH 512
#define NW 512

// db2 decomposition filters
__device__ __constant__ float DLO[4] = {-0.12940952255092145f, 0.22414386804185735f, 0.836516303737469f, 0.48296291314469025f};
__device__ __constant__ float DHI[4] = {-0.48296291314469025f, 0.836516303737469f, -0.22414386804185735f, -0.12940952255092145f};

__device__ inline float wave_max(float v) {
    #pragma unroll
    for (int off = 32; off; off >>= 1) v = fmaxf(v, __shfl_xor(v, off, 64));
    return v;
}

// Level-1 DWT, 4 output rows per block: grid (64, NB), 256 threads = 256 columns.
__global__ __launch_bounds__(256) void k_dwt1(const float* __restrict__ x,
                                              const float* __restrict__ hfw,
                                              float* __restrict__ arr_hf,
                                              float* __restrict__ a1,
                                              float* __restrict__ pbmax1) {
    int b  = blockIdx.y;
    int r0 = blockIdx.x << 2;            // first of 4 output rows
    int c  = threadIdx.x;                // 0..255
    const float* xb = x + (size_t)b * (NH * NW);
    float* arr = arr_hf + (size_t)b * (512 * 512);

    int ca  = (2 * c - 2 + 512) & 511;   // wrapped col pair (2c-2, 2c-1) -- always contiguous
    int cbp = 2 * c;                     // col pair (2c, 2c+1)

    float X[4][4];                        // X[k][l] = x[(2r-2+k)&511][(2c-2+l)&511]
    #pragma unroll
    for (int k = 0; k < 4; ++k) {
        int rr = (2 * r0 - 2 + k + 512) & 511;
        float2 u0 = *(const float2*)(xb + rr * 512 + ca);
        float2 u1 = *(const float2*)(xb + rr * 512 + cbp);
        X[k][0] = u0.x; X[k][1] = u0.y; X[k][2] = u1.x; X[k][3] = u1.y;
    }

    float mad = 0.f, mda = 0.f, mdd = 0.f;

    #pragma unroll
    for (int s = 0; s < 4; ++s) {
        int r = r0 + s;

        float lo[4], hi[4];
        #pragma unroll
        for (int l = 0; l < 4; ++l) {
            float alo = 0.f, ahi = 0.f;
            #pragma unroll
            for (int k = 0; k < 4; ++k) { alo += DLO[3 - k] * X[k][l]; ahi += DHI[3 - k] * X[k][l]; }
            lo[l] = alo; hi[l] = ahi;
        }
        float va = 0.f, vad = 0.f, vda = 0.f, vdd = 0.f;
        #pragma unroll
        for (int l = 0; l < 4; ++l) {
            va  += DLO[3 - l] * lo[l];
            vad += DHI[3 - l] * lo[l];
            vda += DLO[3 - l] * hi[l];
            vdd += DHI[3 - l] * hi[l];
        }

        a1[b * 65536 + r * 256 + c] = va;
        int p_tr = r * 512 + (c + 256);
        int p_bl = (r + 256) * 512 + c;
        int p_br = (r + 256) * 512 + (c + 256);
        arr[p_tr] = vad * hfw[p_tr];
        arr[p_bl] = vda * hfw[p_bl];
        arr[p_br] = vdd * hfw[p_br];

        mad = fmaxf(mad, fabsf(vad));
        mda = fmaxf(mda, fabsf(vda));
        mdd = fmaxf(mdd, fabsf(vdd));

        if (s < 3) {
            #pragma unroll
            for (int l = 0; l < 4; ++l) { X[0][l] = X[2][l]; X[1][l] = X[3][l]; }
            int rr2 = 2 * r + 2;          // <= 510, no wrap needed
            float2 u0 = *(const float2*)(xb + rr2 * 512 + ca);
            float2 u1 = *(const float2*)(xb + rr2 * 512 + cbp);
            X[2][0] = u0.x; X[2][1] = u0.y; X[2][2] = u1.x; X[2][3] = u1.y;
            float2 w0 = *(const float2*)(xb + (rr2 + 1) * 512 + ca);
            float2 w1 = *(const float2*)(xb + (rr2 + 1) * 512 + cbp);
            X[3][0] = w0.x; X[3][1] = w0.y; X[3][2] = w1.x; X[3][3] = w1.y;
        }
    }

    __shared__ float wmax[4][3];
    int wv = threadIdx.x >> 6, ln = threadIdx.x & 63;
    float m0 = wave_max(mad);
    float m1 = wave_max(mda);
    float m2 = wave_max(mdd);
    if (ln == 0) { wmax[wv][0] = m0; wmax[wv][1] = m1; wmax[wv][2] = m2; }
    __syncthreads();
    if (threadIdx.x < 3) {
        int i = threadIdx.x;
        float m = fmaxf(fmaxf(wmax[0][i], wmax[1][i]), fmaxf(wmax[2][i], wmax[3][i]));
        pbmax1[(b * 64 + blockIdx.x) * 3 + i] = m;
    }
}

// Level-2 DWT: a1 -> (a2,ad2,da2,dd2)*hfw into arr top-left; g2 = a2*lfw.
__global__ __launch_bounds__(256) void k_dwt2(const float* __restrict__ a1,
                                              const float* __restrict__ hfw,
                                              const float* __restrict__ lfw,
                                              float* __restrict__ arr_hf,
                                              float* __restrict__ g2,
                                              const float* __restrict__ pbmax1,
                                              float* __restrict__ pbmax2,
                                              float* __restrict__ maxbuf) {
    int b = blockIdx.y;
    int idx = blockIdx.x * 256 + threadIdx.x;
    int r = idx >> 7, c = idx & 127;
    const float* ab = a1 + b * 65536;

    float X[4][4];
    if (r >= 1 && c >= 1) {
        const float* p = ab + (2 * r - 2) * 256 + (2 * c - 2);
        #pragma unroll
        for (int k = 0; k < 4; ++k) {
            float2 u0 = *(const float2*)(p + k * 256);
            float2 u1 = *(const float2*)(p + k * 256 + 2);
            X[k][0] = u0.x; X[k][1] = u0.y; X[k][2] = u1.x; X[k][3] = u1.y;
        }
    } else {
        #pragma unroll
        for (int k = 0; k < 4; ++k) {
            int rr = (2 * r - 2 + k + 256) & 255;
            #pragma unroll
            for (int l = 0; l < 4; ++l) {
                int cc = (2 * c - 2 + l + 256) & 255;
                X[k][l] = ab[rr * 256 + cc];
            }
        }
    }
    float lo[4], hi[4];
    #pragma unroll
    for (int l = 0; l < 4; ++l) {
        float alo = 0.f, ahi = 0.f;
        #pragma unroll
        for (int k = 0; k < 4; ++k) { alo += DLO[3 - k] * X[k][l]; ahi += DHI[3 - k] * X[k][l]; }
        lo[l] = alo; hi[l] = ahi;
    }
    float va = 0.f, vad = 0.f, vda = 0.f, vdd = 0.f;
    #pragma unroll
    for (int l = 0; l < 4; ++l) {
        va  += DLO[3 - l] * lo[l];
        vad += DHI[3 - l] * lo[l];
        vda += DLO[3 - l] * hi[l];
        vdd += DHI[3 - l] * hi[l];
    }

    g2[b * 16384 + r * 128 + c] = va * lfw[r * 128 + c];
    float* arr = arr_hf + (size_t)b * (512 * 512);
    int p_tl = r * 512 + c;
    int p_tr = r * 512 + (c + 128);
    int p_bl = (r + 128) * 512 + c;
    int p_br = (r + 128) * 512 + (c + 128);
    arr[p_tl] = va  * hfw[p_tl];
    arr[p_tr] = vad * hfw[p_tr];
    arr[p_bl] = vda * hfw[p_bl];
    arr[p_br] = vdd * hfw[p_br];

    __shared__ float wmax[4][4];
    int wv = threadIdx.x >> 6, ln = threadIdx.x & 63;
    float m0 = wave_max(fabsf(va));
    float m1 = wave_max(fabsf(vad));
    float m2 = wave_max(fabsf(vda));
    float m3 = wave_max(fabsf(vdd));
    if (ln == 0) { wmax[wv][0] = m0; wmax[wv][1] = m1; wmax[wv][2] = m2; wmax[wv][3] = m3; }
    __syncthreads();
    if (threadIdx.x < 4) {
        int i = threadIdx.x;
        float m = fmaxf(fmaxf(wmax[0][i], wmax[1][i]), fmaxf(wmax[2][i], wmax[3][i]));
        pbmax2[(b * 64 + blockIdx.x) * 4 + i] = m;
    }

    // block 0 of each batch: reduce dwt1's 64x3 per-block maxes -> level-1 finals
    if (blockIdx.x == 0 && threadIdx.x < 64) {
        const float* p1 = pbmax1 + (size_t)(b * 64 + threadIdx.x) * 3;
        float q0 = wave_max(p1[0]);
        float q1 = wave_max(p1[1]);
        float q2 = wave_max(p1[2]);
        if (threadIdx.x == 0) {
            maxbuf[b * 8 + 0] = q0;
            maxbuf[b * 8 + 1] = q1;
            maxbuf[b * 8 + 2] = q2;
        }
    }
}

// select normalization reciprocal by quadrant
__device__ __forceinline__ float quad_inv(int gh, int gw,
                                          float inv_ad1, float inv_da1, float inv_dd1,
                                          float inv_a2, float inv_ad2, float inv_da2, float inv_dd2) {
    if (gh < 256) {
        if (gw < 256) {
            if (gh < 128) return (gw < 128) ? inv_a2 : inv_ad2;
            else          return (gw < 128) ? inv_da2 : inv_dd2;
        }
        return inv_ad1;
    }
    return (gw < 256) ? inv_da1 : inv_dd1;
}

// bilinear sample of g2 (a2*lfw) at output pixel (gh,gw); * inv_a2 applied by caller
__device__ __forceinline__ float bilin_g2(const float* __restrict__ g2b, int gh, int gw) {
    float sh = fminf(fmaxf(0.25f * (float)gh - 0.375f, 0.f), 127.f);
    float sw = fminf(fmaxf(0.25f * (float)gw - 0.375f, 0.f), 127.f);
    int r0 = (int)sh; float fr = sh - (float)r0; int r1 = min(r0 + 1, 127);
    int c0 = (int)sw; float fc = sw - (float)c0; int c1 = min(c0 + 1, 127);
    float g00 = g2b[r0 * 128 + c0];
    float g01 = g2b[r0 * 128 + c1];
    float g10 = g2b[r1 * 128 + c0];
    float g11 = g2b[r1 * 128 + c1];
    float t0 = g00 * (1.f - fr) + g10 * fr;
    float t1 = g01 * (1.f - fr) + g11 * fr;
    return t0 * (1.f - fc) + t1 * fc;
}

// Fused conv stage, 2-tile pipelined. Compute split into TWO sequential 8-oc passes
// (#pragma unroll 1) -> acc[8][4]=32 VGPR live -> ~6 waves/SIMD (measured optimum:
// 16-oc=91us R15, 8-oc=80us R16/R18, 4-oc=124us R17, 256-wide=91us R19).
__global__ __launch_bounds__(256) void k_conv(const float* __restrict__ arr_hf,
                                              const float* __restrict__ g2,
                                              const float* __restrict__ maxbuf,
                                              const float* __restrict__ pbmax2,
                                              const float* __restrict__ cw,
                                              const float* __restrict__ cb,
                                              float* __restrict__ out) {
    int b   = blockIdx.z;
    int th0 = blockIdx.y * 16;           // tile0: rows th0..th0+7, tile1: +8
    int tw0 = blockIdx.x * 128;
    int tid = threadIdx.x;

    __shared__ __align__(16) float tile[2][2][10][132];   // [buf][ch][row][col]
    __shared__ float l2max[4];

    // wave 0: reduce level-2 per-block maxes (64 float4, L2-hot)
    if (tid < 64) {
        float4 m4 = *(const float4*)(pbmax2 + (size_t)(b * 64 + tid) * 4);
        float q0 = wave_max(m4.x);
        float q1 = wave_max(m4.y);
        float q2 = wave_max(m4.z);
        float q3 = wave_max(m4.w);
        if (tid == 0) { l2max[0] = q0; l2max[1] = q1; l2max[2] = q2; l2max[3] = q3; }
    }
    __syncthreads();

    float inv_ad1 = 1.f / maxbuf[b * 8 + 0];
    float inv_da1 = 1.f / maxbuf[b * 8 + 1];
    float inv_dd1 = 1.f / maxbuf[b * 8 + 2];
    float inv_a2  = 1.f / l2max[0];
    float inv_ad2 = 1.f / l2max[1];
    float inv_da2 = 1.f / l2max[2];
    float inv_dd2 = 1.f / l2max[3];

    const float* arr = arr_hf + (size_t)b * (512 * 512);
    const float* g2b = g2 + b * 16384;

    int wq  = tid & 31;   // w-quad: w0 = 4*wq
    int row = tid >> 5;   // output row within tile: 0..7
    size_t plane = 512 * 512;

    // ---- stage tile0 (full) ----
    for (int i = tid; i < 10 * 130; i += 256) {
        int r_ = i / 130;
        int col = i - r_ * 130;
        int gh = th0 + r_ - 1;
        int gw = tw0 + col - 1;
        float v0 = 0.f, v1 = 0.f;
        if (gh >= 0 && gh < 512 && gw >= 0 && gw < 512) {
            v0 = arr[gh * 512 + gw] * quad_inv(gh, gw, inv_ad1, inv_da1, inv_dd1, inv_a2, inv_ad2, inv_da2, inv_dd2);
            v1 = bilin_g2(g2b, gh, gw) * inv_a2;
        }
        tile[0][0][r_][col] = v0;
        tile[0][1][r_][col] = v1;
    }
    __syncthreads();

    // ---- prefetch tile1's arr values into registers ----
    float pre[6];
    #pragma unroll
    for (int it = 0; it < 6; ++it) {
        int i = tid + it * 256;
        float pv = 0.f;
        if (i < 1300) {
            int r_ = i / 130;
            int col = i - r_ * 130;
            int gh = th0 + 8 + r_ - 1;
            int gw = tw0 + col - 1;
            if (gh >= 0 && gh < 512 && gw >= 0 && gw < 512) pv = arr[gh * 512 + gw];
        }
        pre[it] = pv;
    }

    // ---- compute + store tile0 (two 8-oc passes) ----
    #pragma unroll 1
    for (int half = 0; half < 2; ++half) {
        float acc[8][4];
        #pragma unroll
        for (int oc = 0; oc < 8; ++oc) {
            float bvv = cb[half * 8 + oc];
            #pragma unroll
            for (int j = 0; j < 4; ++j) acc[oc][j] = bvv;
        }
        #pragma unroll
        for (int ic = 0; ic < 2; ++ic)
            #pragma unroll
            for (int kh = 0; kh < 3; ++kh) {
                const float* rp_ = &tile[0][ic][row + kh][4 * wq];
                float v[6];
                { float4 t = *(const float4*)rp_; v[0] = t.x; v[1] = t.y; v[2] = t.z; v[3] = t.w;
                  float2 s = *(const float2*)(rp_ + 4); v[4] = s.x; v[5] = s.y; }
                #pragma unroll
                for (int kw = 0; kw < 3; ++kw)
                    #pragma unroll
                    for (int oc = 0; oc < 8; ++oc) {
                        float wv = cw[(half * 8 + oc) * 18 + ic * 9 + kh * 3 + kw];
                        #pragma unroll
                        for (int j = 0; j < 4; ++j)
                            acc[oc][j] = fmaf(v[j + kw], wv, acc[oc][j]);
                    }
            }
        float* ob = out + (size_t)(b * 16 + half * 8) * plane + (size_t)(th0 + row) * 512 + tw0 + 4 * wq;
        #pragma unroll
        for (int oc = 0; oc < 8; ++oc) {
            float4 val = make_float4(acc[oc][0], acc[oc][1], acc[oc][2], acc[oc][3]);
            *(float4*)(ob + (size_t)oc * plane) = val;
        }
    }

    // ---- finish staging tile1 ----
    #pragma unroll
    for (int it = 0; it < 6; ++it) {
        int i = tid + it * 256;
        if (i < 1300) {
            int r_ = i / 130;
            int col = i - r_ * 130;
            int gh = th0 + 8 + r_ - 1;
            int gw = tw0 + col - 1;
            float v0 = 0.f, v1 = 0.f;
            if (gh >= 0 && gh < 512 && gw >= 0 && gw < 512) {
                v0 = pre[it] * quad_inv(gh, gw, inv_ad1, inv_da1, inv_dd1, inv_a2, inv_ad2, inv_da2, inv_dd2);
                v1 = bilin_g2(g2b, gh, gw) * inv_a2;
            }
            tile[1][0][r_][col] = v0;
            tile[1][1][r_][col] = v1;
        }
    }
    __syncthreads();

    // ---- compute + store tile1 (two 8-oc passes) ----
    #pragma unroll 1
    for (int half = 0; half < 2; ++half) {
        float acc[8][4];
        #pragma unroll
        for (int oc = 0; oc < 8; ++oc) {
            float bvv = cb[half * 8 + oc];
            #pragma unroll
            for (int j = 0; j < 4; ++j) acc[oc][j] = bvv;
        }
        #pragma unroll
        for (int ic = 0; ic < 2; ++ic)
            #pragma unroll
            for (int kh = 0; kh < 3; ++kh) {
                const float* rp_ = &tile[1][ic][row + kh][4 * wq];
                float v[6];
                { float4 t = *(const float4*)rp_; v[0] = t.x; v[1] = t.y; v[2] = t.z; v[3] = t.w;
                  float2 s = *(const float2*)(rp_ + 4); v[4] = s.x; v[5] = s.y; }
                #pragma unroll
                for (int kw = 0; kw < 3; ++kw)
                    #pragma unroll
                    for (int oc = 0; oc < 8; ++oc) {
                        float wv = cw[(half * 8 + oc) * 18 + ic * 9 + kh * 3 + kw];
                        #pragma unroll
                        for (int j = 0; j < 4; ++j)
                            acc[oc][j] = fmaf(v[j + kw], wv, acc[oc][j]);
                    }
            }
        float* ob = out + (size_t)(b * 16 + half * 8) * plane + (size_t)(th0 + 8 + row) * 512 + tw0 + 4 * wq;
        #pragma unroll
        for (int oc = 0; oc < 8; ++oc) {
            float4 val = make_float4(acc[oc][0], acc[oc][1], acc[oc][2], acc[oc][3]);
            *(float4*)(ob + (size_t)oc * plane) = val;
        }
    }
}

extern "C" void kernel_launch(void* const* d_in, const int* in_sizes, int n_in,
                              void* d_out, int out_size, void* d_ws, size_t ws_size,
                              hipStream_t stream) {
    const float* x   = (const float*)d_in[0];
    const float* hfw = (const float*)d_in[1];
    const float* lfw = (const float*)d_in[2];
    const float* cw  = (const float*)d_in[3];
    const float* cb  = (const float*)d_in[4];
    float* out = (float*)d_out;

    char* ws = (char*)d_ws;
    float* arr_hf = (float*)(ws);                    // 16 MiB: 16 x 512 x 512 (pre-multiplied by hfw)
    float* a1     = (float*)(ws + 16777216);         //  4 MiB: 16 x 256 x 256
    float* g2     = (float*)(ws + 20971520);         //  1 MiB: 16 x 128 x 128 (a2 * lfw)
    float* maxbuf = (float*)(ws + 22020096);         //  16 x 8 f32 (level-1 finals)
    float* pbmax1 = (float*)(ws + 22020608);         //  16 x 64 x 3 f32
    float* pbmax2 = (float*)(ws + 22033408);         //  16 x 64 x 4 f32 (float4-aligned)

    k_dwt1<<<dim3(64, NB), 256, 0, stream>>>(x, hfw, arr_hf, a1, pbmax1);
    k_dwt2<<<dim3(64, NB), 256, 0, stream>>>(a1, hfw, lfw, arr_hf, g2, pbmax1, pbmax2, maxbuf);
    k_conv<<<dim3(4, 32, NB), 256, 0, stream>>>(arr_hf, g2, maxbuf, pbmax2, cw, cb, out);
}